// Round 11
// baseline (906.154 us; speedup 1.0000x reference)
//
#include <hip/hip_runtime.h>
#include <hip/hip_bf16.h>

#define N_NODES 50000
#define DEG     16
#define IN_CH   128
#define TYPE_DIM 32
#define F_DIM   160      // = IN_CH + TYPE_DIM
#define H_DIM   160
#define OUT_CH  128
#define NSTEP   16       // = DEG timesteps
#define LS      168      // LDS row stride in ushorts (16B-aligned)
#define NRES    11       // LDS-resident frags/wave: kc5 p0-3, kc6 p0-3, kc7 p0-2

typedef short  bf16x8 __attribute__((ext_vector_type(8)));
typedef float  f32x4  __attribute__((ext_vector_type(4)));
typedef unsigned int u32x4 __attribute__((ext_vector_type(4)));

// Workspace in __device__ globals (cached VRAM) — d_ws is mapped
// uncached/streaming. Fully rewritten every call.
__device__ ushort g_hin[N_NODES * F_DIM];       // 16,000,000 B
__device__ ushort g_wfrag[400 * 64 * 8];        // 409,600 B
__device__ ushort g_wlrfrag[80 * 64 * 8];       // 81,920 B
__device__ float  g_bsum[4 * H_DIM];            // 2,560 B

static __device__ __forceinline__ ushort f2bf(float v) {
    union { float f; unsigned u; } x; x.f = v;
    unsigned r = x.u + 0x7fff + ((x.u >> 16) & 1);   // RNE
    return (ushort)(r >> 16);
}
// v_rcp_f32 (1 instr) instead of IEEE division (~9 instr): R1 proved real win.
static __device__ __forceinline__ float sigmoid_fast(float x) {
    return __builtin_amdgcn_rcpf(1.f + __expf(-x));
}
static __device__ __forceinline__ float tanh_fast(float x) {
    float e = __expf(2.f * x);
    return 1.f - 2.f * __builtin_amdgcn_rcpf(e + 1.f);
}

// ---------------------------------------------------------------------------
// Pack weights into MFMA B-fragment order (bf16), and sum biases.
// Main W frags: frag = qg*40 + kc*4 + p   (qg 0..9, kc 0..9 K-chunk, p gate)
//   kc<5 -> W_ih (X part), kc>=5 -> W_hh (H part)
// Final W frags: frag = kc*8 + nt : row = nt*16+(lane&15), k<160 -> W_l, else W_r
// ---------------------------------------------------------------------------
__global__ void pack_kernel(const float* __restrict__ Wih, const float* __restrict__ Whh,
                            const float* __restrict__ bih, const float* __restrict__ bhh,
                            const float* __restrict__ Wl,  const float* __restrict__ Wr)
{
    int gid = blockIdx.x * 256 + threadIdx.x;
    if (gid < 400 * 64) {
        int frag = gid >> 6, lane = gid & 63;
        int p = frag & 3, kc = (frag >> 2) % 10, qg = frag / 40;
        int row = p * 160 + qg * 16 + (lane & 15);
        int quad = lane >> 4;
        const float* src; int k0;
        if (kc < 5) { src = Wih + row * 160; k0 = kc * 32 + quad * 8; }
        else        { src = Whh + row * 160; k0 = (kc - 5) * 32 + quad * 8; }
        ushort tmp[8];
        #pragma unroll
        for (int j = 0; j < 8; j++) tmp[j] = f2bf(src[k0 + j]);
        ((u32x4*)g_wfrag)[frag * 64 + lane] = *(const u32x4*)tmp;
    } else if (gid < 400 * 64 + 80 * 64) {
        int g2 = gid - 400 * 64;
        int frag = g2 >> 6, lane = g2 & 63;
        int nt = frag & 7, kc = frag >> 3;
        int row = nt * 16 + (lane & 15);
        int quad = lane >> 4;
        int k0 = kc * 32 + quad * 8;
        ushort tmp[8];
        #pragma unroll
        for (int j = 0; j < 8; j++) {
            int k = k0 + j;
            float v = (k < 160) ? Wl[row * 160 + k] : Wr[row * 160 + (k - 160)];
            tmp[j] = f2bf(v);
        }
        ((u32x4*)g_wlrfrag)[frag * 64 + lane] = *(const u32x4*)tmp;
    } else if (gid < 400 * 64 + 80 * 64 + 640) {
        int i = gid - (400 * 64 + 80 * 64);
        g_bsum[i] = bih[i] + bhh[i];
    }
}

// h_in = concat(x, emb[type]) as bf16 rows of 160 (320 B, 16B aligned)
__global__ void build_hin(const float* __restrict__ x, const int* __restrict__ tids,
                          const float* __restrict__ emb)
{
    int i = blockIdx.x * 256 + threadIdx.x;
    if (i >= N_NODES * F_DIM) return;
    int n = i / F_DIM, d = i - n * F_DIM;
    float v = (d < IN_CH) ? x[n * IN_CH + d] : emb[tids[n] * TYPE_DIM + (d - IN_CH)];
    g_hin[i] = f2bf(v);
}

// ---------------------------------------------------------------------------
// R11 = R8 (687us, best) + kc8 p0-3 in PINNED registers (asm-forced).
// R10 post-mortem: passive wreg8[] was rematerialized (VGPR stayed 84) and
// the hoist/sink perturbation doubled FETCH (294->713MB) -> +120us. The
// 25-frag point of the frag-count law (40->1012, 33->750, 29->687) was
// never actually measured. Fix: named w8p0..3 + asm volatile "+v" pin — an
// opaque redefinition the compiler cannot recompute from the loads, forcing
// the 16 VGPRs live across the t-loop.
// Budget: 84 + 16 + 64 acc = 164 <= 168 (3 waves/SIMD quantum);
// launch_bounds(640,3) keeps the allocator inside it.
// Pre-committed reads: VGPR ~96-110 = pin OK; dur 615-655 = law holds;
// dur ~690 = law flattened (declare ceiling next); WRITE>150MB = spill.
// LDS: 43008 (Xb,Hb) + 112640 (resident) = 155648 <= 160KB (dynamic).
// ---------------------------------------------------------------------------
__launch_bounds__(640, 3)
__global__ void lstm_sage_r11(const int* __restrict__ edge_src,
                              const float* __restrict__ bl,
                              float* __restrict__ out)
{
    extern __shared__ ushort lds[];
    constexpr int BSZ  = 64 * LS;      // 10752 ushorts = 21504 B
    constexpr int XOFF = 0;            // Xb (single buffer)
    constexpr int HOFF = BSZ;          // Hb (single buffer)
    constexpr int WOFF = 2 * BSZ;      // resident weights: 11 frags x 10 waves

    const int tid  = threadIdx.x;
    const int lane = tid & 63;
    const int wv   = tid >> 6;           // 0..9 = qg group
    const int col  = lane & 15, quad = lane >> 4;
    const int nb   = blockIdx.x * 64;

    float bG4[4];
    #pragma unroll
    for (int p = 0; p < 4; p++) bG4[p] = g_bsum[p * 160 + wv * 16 + col];

    for (int i = tid; i < BSZ; i += 640) lds[HOFF + i] = 0;   // h(-1) = 0

    float c_st[4][4];
    #pragma unroll
    for (int m = 0; m < 4; m++)
        #pragma unroll
        for (int r = 0; r < 4; r++) c_st[m][r] = 0.f;

    unsigned hn[4][2];                   // h(t) staging regs (packed bf16 pairs)

    const int grow  = tid / 10;          // 64 rows x 10 threads
    const int gpart = tid - grow * 10;   // 0..9 -> segs gpart, gpart+10
    const int node_g = nb + grow;
    const int own = (node_g < N_NODES ? node_g : 0);
    const int sbase = own * DEG;

    const u32x4* wq = (const u32x4*)g_wfrag + wv * 40 * 64 + lane;

    // ---- LDS-resident weight load: once per block.
    //      f0..3 = kc5 p0..3, f4..7 = kc6 p0..3, f8..10 = kc7 p0..2.
    //      Layout: (wv*NRES+f)*64 + lane (u32x4 units). Wave-private region.
    {
        u32x4* wl = (u32x4*)(lds + WOFF) + wv * (NRES * 64) + lane;
        #pragma unroll
        for (int f = 0; f < NRES; f++) {
            int kcp = (f < 8) ? (5 * 4 + f) : (7 * 4 + (f - 8));
            wl[f * 64] = wq[kcp * 64];
        }
    }
    const u32x4* wlr = (const u32x4*)(lds + WOFF) + wv * (NRES * 64) + lane;

    // ---- REGISTER-resident kc8 p0..3: named + asm-pinned (16 VGPR).
    //      The "+v" redefinition is opaque -> rematerialization illegal.
    bf16x8 w8p0, w8p1, w8p2, w8p3;
    {
        u32x4 u0 = wq[(8 * 4 + 0) * 64];
        u32x4 u1 = wq[(8 * 4 + 1) * 64];
        u32x4 u2 = wq[(8 * 4 + 2) * 64];
        u32x4 u3 = wq[(8 * 4 + 3) * 64];
        w8p0 = *(const bf16x8*)&u0;
        w8p1 = *(const bf16x8*)&u1;
        w8p2 = *(const bf16x8*)&u2;
        w8p3 = *(const bf16x8*)&u3;
        asm volatile("" : "+v"(w8p0), "+v"(w8p1), "+v"(w8p2), "+v"(w8p3));
    }

    // prologue: park X(0) (plain cacheable loads; ~16x reuse per g_hin row)
    u32x4 P0, P1;
    {
        int s = edge_src[sbase];
        const u32x4* sp = (const u32x4*)(g_hin + s * F_DIM);
        P0 = sp[gpart]; P1 = sp[gpart + 10];
    }
    int snext = edge_src[sbase + 1];

    const int aoff = col * LS + quad * 8;           // A-frag offset within buffer

    #pragma unroll 1
    for (int t = 0; t < NSTEP; t++) {
        // ---- commit h(t-1) regs and parked X(t) to LDS (pre-barrier window)
        if (t > 0) {
            #pragma unroll
            for (int m = 0; m < 4; m++)
                #pragma unroll
                for (int k = 0; k < 2; k++) {
                    int a = (m * 16 + quad * 4 + 2 * k) * LS + wv * 16 + col;
                    unsigned pk = hn[m][k];
                    lds[HOFF + a]      = (ushort)pk;
                    lds[HOFF + a + LS] = (ushort)(pk >> 16);
                }
        }
        {
            u32x4* dp = (u32x4*)(lds + XOFF + grow * LS);
            dp[gpart] = P0; dp[gpart + 10] = P1;
        }
        __syncthreads();

        // ---- park next gather (t=15: own h_in row for the epilogue)
        {
            const u32x4* sp = (t < NSTEP - 1)
                ? (const u32x4*)(g_hin + snext * F_DIM)
                : (const u32x4*)(g_hin + own * F_DIM);
            P0 = sp[gpart]; P1 = sp[gpart + 10];
            snext = edge_src[sbase + ((t + 2 < DEG) ? t + 2 : 0)];
        }

        f32x4 acc[4][4];
        #pragma unroll
        for (int m = 0; m < 4; m++)
            #pragma unroll
            for (int p = 0; p < 4; p++)
                acc[m][p] = (f32x4){bG4[p], bG4[p], bG4[p], bG4[p]};

        // ---- kc loop: kc5/kc6 + kc7 p0-2 from LDS; kc8 from pinned regs;
        //      kc0-4, kc7p3, kc9 streamed from L2 (25 frags).
        #pragma unroll
        for (int kc = 0; kc < 10; kc++) {
            bf16x8 bfr[4];
            if (kc == 8) {
                bfr[0] = w8p0; bfr[1] = w8p1; bfr[2] = w8p2; bfr[3] = w8p3;
            } else {
                #pragma unroll
                for (int p = 0; p < 4; p++) {
                    u32x4 u;
                    if (kc == 5)               u = wlr[p * 64];
                    else if (kc == 6)          u = wlr[(4 + p) * 64];
                    else if (kc == 7 && p < 3) u = wlr[(8 + p) * 64];
                    else                       u = wq[(kc * 4 + p) * 64];
                    bfr[p] = *(const bf16x8*)&u;
                }
            }
            const ushort* ab = ((kc < 5) ? (lds + XOFF + kc * 32)
                                         : (lds + HOFF + (kc - 5) * 32)) + aoff;
            bf16x8 afr[4];
            #pragma unroll
            for (int m = 0; m < 4; m++)
                afr[m] = *(const bf16x8*)(ab + m * (16 * LS));
            #pragma unroll
            for (int m = 0; m < 4; m++)
                #pragma unroll
                for (int p = 0; p < 4; p++)
                    acc[m][p] = __builtin_amdgcn_mfma_f32_16x16x32_bf16(
                        afr[m], bfr[p], acc[m][p], 0, 0, 0);
        }

        // ---- elementwise -> h(t) staged in regs (committed next loop top)
        #pragma unroll
        for (int m = 0; m < 4; m++) {
            #pragma unroll
            for (int k = 0; k < 2; k++) {
                unsigned pk = 0;
                #pragma unroll
                for (int h2 = 0; h2 < 2; h2++) {
                    int r = 2 * k + h2;
                    float c = sigmoid_fast(acc[m][1][r]) * c_st[m][r]
                            + sigmoid_fast(acc[m][0][r]) * tanh_fast(acc[m][2][r]);
                    c_st[m][r] = c;
                    float h = sigmoid_fast(acc[m][3][r]) * tanh_fast(c);
                    pk |= ((unsigned)f2bf(h)) << (16 * h2);
                }
                hn[m][k] = pk;
            }
        }
        __syncthreads();
    }

    // ---- final commit: Hb = h(15), Xb = own h_in rows (parked at t=15)
    #pragma unroll
    for (int m = 0; m < 4; m++)
        #pragma unroll
        for (int k = 0; k < 2; k++) {
            int a = (m * 16 + quad * 4 + 2 * k) * LS + wv * 16 + col;
            unsigned pk = hn[m][k];
            lds[HOFF + a]      = (ushort)pk;
            lds[HOFF + a + LS] = (ushort)(pk >> 16);
        }
    {
        u32x4* dp = (u32x4*)(lds + XOFF + grow * LS);
        dp[gpart] = P0; dp[gpart + 10] = P1;
    }
    __syncthreads();

    // ---- out = relu([h_last | h_in] @ [W_l | W_r]^T + b_l)
    // waves 0..7: (m = wv&3, phalf = wv>>2); waves 8,9 idle (no barriers after)
    if (wv < 8) {
        const int m = wv & 3, pb = (wv >> 2) * 4;
        f32x4 acc2[4];
        #pragma unroll
        for (int p = 0; p < 4; p++) {
            float b = bl[(pb + p) * 16 + col];
            acc2[p] = (f32x4){b, b, b, b};
        }
        const u32x4* wq2 = (const u32x4*)g_wlrfrag + lane;
        #pragma unroll
        for (int kc = 0; kc < 10; kc++) {
            bf16x8 bfr[4];
            #pragma unroll
            for (int p = 0; p < 4; p++) {
                u32x4 u = wq2[(kc * 8 + pb + p) * 64];
                bfr[p] = *(const bf16x8*)&u;
            }
            const ushort* ab = ((kc < 5) ? (lds + HOFF + kc * 32)
                                         : (lds + XOFF + (kc - 5) * 32))
                               + (m * 16 + col) * LS + quad * 8;
            bf16x8 afr = *(const bf16x8*)ab;
            #pragma unroll
            for (int p = 0; p < 4; p++)
                acc2[p] = __builtin_amdgcn_mfma_f32_16x16x32_bf16(afr, bfr[p], acc2[p], 0, 0, 0);
        }
        #pragma unroll
        for (int p = 0; p < 4; p++) {
            int ocol = (pb + p) * 16 + col;
            #pragma unroll
            for (int r = 0; r < 4; r++) {
                int node = nb + m * 16 + quad * 4 + r;
                if (node < N_NODES) {
                    float v = acc2[p][r];
                    out[node * OUT_CH + ocol] = v > 0.f ? v : 0.f;
                }
            }
        }
    }
}

// ---------------------------------------------------------------------------
// FALLBACK: static 43KB LDS, 2 barriers/step, all weights streamed — used
// only if the dynamic-LDS attribute probe fails.
// ---------------------------------------------------------------------------
__launch_bounds__(640)
__global__ void lstm_sage_sb(const int* __restrict__ edge_src,
                             const float* __restrict__ bl,
                             float* __restrict__ out)
{
    __shared__ ushort Xb[64 * LS];
    __shared__ ushort Hb[64 * LS];

    const int tid  = threadIdx.x;
    const int lane = tid & 63;
    const int wv   = tid >> 6;
    const int col  = lane & 15, quad = lane >> 4;
    const int nb   = blockIdx.x * 64;

    float bG4[4];
    #pragma unroll
    for (int p = 0; p < 4; p++) bG4[p] = g_bsum[p * 160 + wv * 16 + col];

    for (int i = tid; i < 64 * LS; i += 640) Hb[i] = 0;

    float c_st[4][4];
    #pragma unroll
    for (int m = 0; m < 4; m++)
        #pragma unroll
        for (int r = 0; r < 4; r++) c_st[m][r] = 0.f;

    unsigned hn[4][2];

    const int grow  = tid / 10;
    const int gpart = tid - grow * 10;
    const int node_g = nb + grow;
    const int sbase = (node_g < N_NODES ? node_g : 0) * DEG;

    u32x4 P0, P1;
    {
        int s = edge_src[sbase];
        const u32x4* sp = (const u32x4*)(g_hin + s * F_DIM);
        P0 = sp[gpart]; P1 = sp[gpart + 10];
    }
    int snext = edge_src[sbase + 1];

    #pragma unroll 1
    for (int t = 0; t < NSTEP; t++) {
        if (t > 0) {
            #pragma unroll
            for (int m = 0; m < 4; m++)
                #pragma unroll
                for (int k = 0; k < 2; k++) {
                    int a = (m * 16 + quad * 4 + 2 * k) * LS + wv * 16 + col;
                    unsigned pk = hn[m][k];
                    Hb[a]      = (ushort)pk;
                    Hb[a + LS] = (ushort)(pk >> 16);
                }
        }
        {
            u32x4* dp = (u32x4*)(Xb + grow * LS);
            dp[gpart] = P0; dp[gpart + 10] = P1;
        }
        __syncthreads();

        {
            const u32x4* sp = (t < NSTEP - 1)
                ? (const u32x4*)(g_hin + snext * F_DIM)
                : (const u32x4*)(g_hin + (node_g < N_NODES ? node_g : 0) * F_DIM);
            P0 = sp[gpart]; P1 = sp[gpart + 10];
            snext = edge_src[sbase + ((t + 2 < DEG) ? t + 2 : 0)];
        }

        f32x4 acc[4][4];
        #pragma unroll
        for (int m = 0; m < 4; m++)
            #pragma unroll
            for (int p = 0; p < 4; p++)
                acc[m][p] = (f32x4){bG4[p], bG4[p], bG4[p], bG4[p]};

        const u32x4* wq = (const u32x4*)g_wfrag + wv * 40 * 64 + lane;
        #pragma unroll
        for (int kc = 0; kc < 10; kc++) {
            bf16x8 bfr[4];
            #pragma unroll
            for (int p = 0; p < 4; p++) {
                u32x4 u = wq[(kc * 4 + p) * 64];
                bfr[p] = *(const bf16x8*)&u;
            }
            const ushort* ab = ((kc < 5) ? (Xb + kc * 32) : (Hb + (kc - 5) * 32))
                               + col * LS + quad * 8;
            bf16x8 afr[4];
            #pragma unroll
            for (int m = 0; m < 4; m++)
                afr[m] = *(const bf16x8*)(ab + m * (16 * LS));
            #pragma unroll
            for (int m = 0; m < 4; m++)
                #pragma unroll
                for (int p = 0; p < 4; p++)
                    acc[m][p] = __builtin_amdgcn_mfma_f32_16x16x32_bf16(
                        afr[m], bfr[p], acc[m][p], 0, 0, 0);
        }
        #pragma unroll
        for (int m = 0; m < 4; m++) {
            #pragma unroll
            for (int k = 0; k < 2; k++) {
                unsigned pk = 0;
                #pragma unroll
                for (int h2 = 0; h2 < 2; h2++) {
                    int r = 2 * k + h2;
                    float c = sigmoid_fast(acc[m][1][r]) * c_st[m][r]
                            + sigmoid_fast(acc[m][0][r]) * tanh_fast(acc[m][2][r]);
                    c_st[m][r] = c;
                    float h = sigmoid_fast(acc[m][3][r]) * tanh_fast(c);
                    pk |= ((unsigned)f2bf(h)) << (16 * h2);
                }
                hn[m][k] = pk;
            }
        }
        __syncthreads();
    }

    #pragma unroll
    for (int m = 0; m < 4; m++)
        #pragma unroll
        for (int k = 0; k < 2; k++) {
            int a = (m * 16 + quad * 4 + 2 * k) * LS + wv * 16 + col;
            unsigned pk = hn[m][k];
            Hb[a]      = (ushort)pk;
            Hb[a + LS] = (ushort)(pk >> 16);
        }
    {
        u32x4* dp = (u32x4*)(Xb + grow * LS);
        dp[gpart] = P0; dp[gpart + 10] = P1;
    }
    __syncthreads();

    if (wv < 8) {
        const int m = wv & 3, pb = (wv >> 2) * 4;
        f32x4 acc[4];
        #pragma unroll
        for (int p = 0; p < 4; p++) {
            float b = bl[(pb + p) * 16 + col];
            acc[p] = (f32x4){b, b, b, b};
        }
        const u32x4* wq2 = (const u32x4*)g_wlrfrag + lane;
        #pragma unroll
        for (int kc = 0; kc < 10; kc++) {
            bf16x8 bfr[4];
            #pragma unroll
            for (int p = 0; p < 4; p++) {
                u32x4 u = wq2[(kc * 8 + pb + p) * 64];
                bfr[p] = *(const bf16x8*)&u;
            }
            const ushort* ab = ((kc < 5) ? (Hb + kc * 32) : (Xb + (kc - 5) * 32))
                               + (m * 16 + col) * LS + quad * 8;
            bf16x8 afr = *(const bf16x8*)ab;
            #pragma unroll
            for (int p = 0; p < 4; p++)
                acc[p] = __builtin_amdgcn_mfma_f32_16x16x32_bf16(afr, bfr[p], acc[p], 0, 0, 0);
        }
        #pragma unroll
        for (int p = 0; p < 4; p++) {
            int ocol = (pb + p) * 16 + col;
            #pragma unroll
            for (int r = 0; r < 4; r++) {
                int node = nb + m * 16 + quad * 4 + r;
                if (node < N_NODES) {
                    float v = acc[p][r];
                    out[node * OUT_CH + ocol] = v > 0.f ? v : 0.f;
                }
            }
        }
    }
}

extern "C" void kernel_launch(void* const* d_in, const int* in_sizes, int n_in,
                              void* d_out, int out_size, void* d_ws, size_t ws_size,
                              hipStream_t stream)
{
    const float* x      = (const float*)d_in[0];
    const int*   tids   = (const int*)  d_in[1];
    const int*   esrc   = (const int*)  d_in[2];   // edge_index[0] = src (dst sorted, DEG each)
    const float* emb    = (const float*)d_in[3];
    const float* Wih    = (const float*)d_in[4];
    const float* Whh    = (const float*)d_in[5];
    const float* bih    = (const float*)d_in[6];
    const float* bhh    = (const float*)d_in[7];
    const float* Wl     = (const float*)d_in[8];
    const float* blin   = (const float*)d_in[9];
    const float* Wr     = (const float*)d_in[10];
    float* out = (float*)d_out;

    hipLaunchKernelGGL(pack_kernel, dim3(123), dim3(256), 0, stream,
                       Wih, Whh, bih, bhh, Wl, Wr);
    hipLaunchKernelGGL(build_hin, dim3((N_NODES * F_DIM + 255) / 256), dim3(256), 0, stream,
                       x, tids, emb);

    // 43008 (Xb+Hb single buffers) + 112640 (11 resident frags) = 155648 B
    const int dbShmem = (2 * 64 * LS + NRES * 10 * 64 * 8) * (int)sizeof(ushort);
    (void)hipFuncSetAttribute((const void*)lstm_sage_r11,
                              hipFuncAttributeMaxDynamicSharedMemorySize, dbShmem);
    hipFuncAttributes fa;
    bool dbOk = (hipFuncGetAttributes(&fa, (const void*)lstm_sage_r11) == hipSuccess) &&
                (fa.maxDynamicSharedSizeBytes >= dbShmem);

    if (dbOk) {
        hipLaunchKernelGGL(lstm_sage_r11, dim3((N_NODES + 63) / 64), dim3(640),
                           dbShmem, stream, esrc, blin, out);
    } else {
        hipLaunchKernelGGL(lstm_sage_sb, dim3((N_NODES + 63) / 64), dim3(640),
                           0, stream, esrc, blin, out);
    }
}

// Round 12
// 734.501 us; speedup vs baseline: 1.2337x; 1.2337x over previous
//
#include <hip/hip_runtime.h>
#include <hip/hip_bf16.h>

#define N_NODES 50000
#define DEG     16
#define IN_CH   128
#define TYPE_DIM 32
#define F_DIM   160      // = IN_CH + TYPE_DIM
#define H_DIM   160
#define OUT_CH  128
#define NSTEP   16       // = DEG timesteps
#define LS      168      // LDS row stride in ushorts (16B-aligned)
#define NRES    11       // resident frags/wave: kc5 p0-3, kc6 p0-3, kc7 p0-2

typedef short  bf16x8 __attribute__((ext_vector_type(8)));
typedef float  f32x4  __attribute__((ext_vector_type(4)));
typedef unsigned int u32x4 __attribute__((ext_vector_type(4)));

// Workspace in __device__ globals (cached VRAM) — d_ws is mapped
// uncached/streaming. Fully rewritten every call.
__device__ ushort g_hin[N_NODES * F_DIM];       // 16,000,000 B
__device__ ushort g_wfrag[400 * 64 * 8];        // 409,600 B
__device__ ushort g_wlrfrag[80 * 64 * 8];       // 81,920 B
__device__ float  g_bsum[4 * H_DIM];            // 2,560 B

static __device__ __forceinline__ ushort f2bf(float v) {
    union { float f; unsigned u; } x; x.f = v;
    unsigned r = x.u + 0x7fff + ((x.u >> 16) & 1);   // RNE
    return (ushort)(r >> 16);
}
// v_rcp_f32 (1 instr) instead of IEEE division (~9 instr): R1 proved real win.
static __device__ __forceinline__ float sigmoid_fast(float x) {
    return __builtin_amdgcn_rcpf(1.f + __expf(-x));
}
static __device__ __forceinline__ float tanh_fast(float x) {
    float e = __expf(2.f * x);
    return 1.f - 2.f * __builtin_amdgcn_rcpf(e + 1.f);
}

// ---------------------------------------------------------------------------
// Pack weights into MFMA B-fragment order (bf16), and sum biases.
// Main W frags: frag = qg*40 + kc*4 + p   (qg 0..9, kc 0..9 K-chunk, p gate)
//   kc<5 -> W_ih (X part), kc>=5 -> W_hh (H part)
// Final W frags: frag = kc*8 + nt : row = nt*16+(lane&15), k<160 -> W_l, else W_r
// ---------------------------------------------------------------------------
__global__ void pack_kernel(const float* __restrict__ Wih, const float* __restrict__ Whh,
                            const float* __restrict__ bih, const float* __restrict__ bhh,
                            const float* __restrict__ Wl,  const float* __restrict__ Wr)
{
    int gid = blockIdx.x * 256 + threadIdx.x;
    if (gid < 400 * 64) {
        int frag = gid >> 6, lane = gid & 63;
        int p = frag & 3, kc = (frag >> 2) % 10, qg = frag / 40;
        int row = p * 160 + qg * 16 + (lane & 15);
        int quad = lane >> 4;
        const float* src; int k0;
        if (kc < 5) { src = Wih + row * 160; k0 = kc * 32 + quad * 8; }
        else        { src = Whh + row * 160; k0 = (kc - 5) * 32 + quad * 8; }
        ushort tmp[8];
        #pragma unroll
        for (int j = 0; j < 8; j++) tmp[j] = f2bf(src[k0 + j]);
        ((u32x4*)g_wfrag)[frag * 64 + lane] = *(const u32x4*)tmp;
    } else if (gid < 400 * 64 + 80 * 64) {
        int g2 = gid - 400 * 64;
        int frag = g2 >> 6, lane = g2 & 63;
        int nt = frag & 7, kc = frag >> 3;
        int row = nt * 16 + (lane & 15);
        int quad = lane >> 4;
        int k0 = kc * 32 + quad * 8;
        ushort tmp[8];
        #pragma unroll
        for (int j = 0; j < 8; j++) {
            int k = k0 + j;
            float v = (k < 160) ? Wl[row * 160 + k] : Wr[row * 160 + (k - 160)];
            tmp[j] = f2bf(v);
        }
        ((u32x4*)g_wlrfrag)[frag * 64 + lane] = *(const u32x4*)tmp;
    } else if (gid < 400 * 64 + 80 * 64 + 640) {
        int i = gid - (400 * 64 + 80 * 64);
        g_bsum[i] = bih[i] + bhh[i];
    }
}

// h_in = concat(x, emb[type]) as bf16 rows of 160 (320 B, 16B aligned)
__global__ void build_hin(const float* __restrict__ x, const int* __restrict__ tids,
                          const float* __restrict__ emb)
{
    int i = blockIdx.x * 256 + threadIdx.x;
    if (i >= N_NODES * F_DIM) return;
    int n = i / F_DIM, d = i - n * F_DIM;
    float v = (d < IN_CH) ? x[n * IN_CH + d] : emb[tids[n] * TYPE_DIM + (d - IN_CH)];
    g_hin[i] = f2bf(v);
}

// ---------------------------------------------------------------------------
// R12 = byte-identical revert to R8 (687us, session best).
// R10/R11 post-mortem: both attempts to move a 12th+ frag group into
// registers (passive and asm-pinned) left VGPR_Count at 84 and doubled
// FETCH (294->713/753MB) via load-interleave perturbation -> +120-160us.
// The R8 schedule is a codegen artifact whose weight-load interleave keeps
// the streamed set L2-hot; the streamed-frag lever (40->33->29 frags =
// 1012->750->687us, two confirmed predictions) is exhausted:
//   - LDS residency full (155.6 of 160KB),
//   - register residency compiler-refused (R10/R11),
//   - tile growth register-blocked (128-node acc = 212 regs > 170 cap),
//   - latency class irrelevant (R9: FETCH -30% at dur +4%),
//   - occupancy structurally pinned (~148 regs -> 1 block/CU, all rounds).
// Expected reproduction: dur ~687-700, VGPR 84/SGPR 80, FETCH ~294MB.
// ---------------------------------------------------------------------------
__launch_bounds__(640, 3)
__global__ void lstm_sage_r11(const int* __restrict__ edge_src,
                              const float* __restrict__ bl,
                              float* __restrict__ out)
{
    extern __shared__ ushort lds[];
    constexpr int BSZ  = 64 * LS;      // 10752 ushorts = 21504 B
    constexpr int XOFF = 0;            // Xb (single buffer)
    constexpr int HOFF = BSZ;          // Hb (single buffer)
    constexpr int WOFF = 2 * BSZ;      // resident weights: 11 frags x 10 waves

    const int tid  = threadIdx.x;
    const int lane = tid & 63;
    const int wv   = tid >> 6;           // 0..9 = qg group
    const int col  = lane & 15, quad = lane >> 4;
    const int nb   = blockIdx.x * 64;

    float bG4[4];
    #pragma unroll
    for (int p = 0; p < 4; p++) bG4[p] = g_bsum[p * 160 + wv * 16 + col];

    for (int i = tid; i < BSZ; i += 640) lds[HOFF + i] = 0;   // h(-1) = 0

    float c_st[4][4];
    #pragma unroll
    for (int m = 0; m < 4; m++)
        #pragma unroll
        for (int r = 0; r < 4; r++) c_st[m][r] = 0.f;

    unsigned hn[4][2];                   // h(t) staging regs (packed bf16 pairs)

    const int grow  = tid / 10;          // 64 rows x 10 threads
    const int gpart = tid - grow * 10;   // 0..9 -> segs gpart, gpart+10
    const int node_g = nb + grow;
    const int own = (node_g < N_NODES ? node_g : 0);
    const int sbase = own * DEG;

    const u32x4* wq = (const u32x4*)g_wfrag + wv * 40 * 64 + lane;

    // ---- resident weight load: once per block.
    //      f0..3 = kc5 p0..3, f4..7 = kc6 p0..3, f8..10 = kc7 p0..2.
    //      Layout: (wv*NRES+f)*64 + lane (u32x4 units). Wave-private region.
    {
        u32x4* wl = (u32x4*)(lds + WOFF) + wv * (NRES * 64) + lane;
        #pragma unroll
        for (int f = 0; f < NRES; f++) {
            int kcp = (f < 8) ? (5 * 4 + f) : (7 * 4 + (f - 8));
            wl[f * 64] = wq[kcp * 64];
        }
    }
    const u32x4* wlr = (const u32x4*)(lds + WOFF) + wv * (NRES * 64) + lane;

    // prologue: park X(0) (plain cacheable loads; ~16x reuse per g_hin row)
    u32x4 P0, P1;
    {
        int s = edge_src[sbase];
        const u32x4* sp = (const u32x4*)(g_hin + s * F_DIM);
        P0 = sp[gpart]; P1 = sp[gpart + 10];
    }
    int snext = edge_src[sbase + 1];

    const int aoff = col * LS + quad * 8;           // A-frag offset within buffer

    #pragma unroll 1
    for (int t = 0; t < NSTEP; t++) {
        // ---- commit h(t-1) regs and parked X(t) to LDS (pre-barrier window)
        if (t > 0) {
            #pragma unroll
            for (int m = 0; m < 4; m++)
                #pragma unroll
                for (int k = 0; k < 2; k++) {
                    int a = (m * 16 + quad * 4 + 2 * k) * LS + wv * 16 + col;
                    unsigned pk = hn[m][k];
                    lds[HOFF + a]      = (ushort)pk;
                    lds[HOFF + a + LS] = (ushort)(pk >> 16);
                }
        }
        {
            u32x4* dp = (u32x4*)(lds + XOFF + grow * LS);
            dp[gpart] = P0; dp[gpart + 10] = P1;
        }
        __syncthreads();

        // ---- park next gather (t=15: own h_in row for the epilogue)
        {
            const u32x4* sp = (t < NSTEP - 1)
                ? (const u32x4*)(g_hin + snext * F_DIM)
                : (const u32x4*)(g_hin + own * F_DIM);
            P0 = sp[gpart]; P1 = sp[gpart + 10];
            snext = edge_src[sbase + ((t + 2 < DEG) ? t + 2 : 0)];
        }

        f32x4 acc[4][4];
        #pragma unroll
        for (int m = 0; m < 4; m++)
            #pragma unroll
            for (int p = 0; p < 4; p++)
                acc[m][p] = (f32x4){bG4[p], bG4[p], bG4[p], bG4[p]};

        // ---- kc loop: kc5/kc6 fully + kc7 p0-2 from LDS-resident; rest streamed
        #pragma unroll
        for (int kc = 0; kc < 10; kc++) {
            bf16x8 bfr[4];
            #pragma unroll
            for (int p = 0; p < 4; p++) {
                u32x4 u;
                if (kc == 5)               u = wlr[p * 64];
                else if (kc == 6)          u = wlr[(4 + p) * 64];
                else if (kc == 7 && p < 3) u = wlr[(8 + p) * 64];
                else                       u = wq[(kc * 4 + p) * 64];
                bfr[p] = *(const bf16x8*)&u;
            }
            const ushort* ab = ((kc < 5) ? (lds + XOFF + kc * 32)
                                         : (lds + HOFF + (kc - 5) * 32)) + aoff;
            bf16x8 afr[4];
            #pragma unroll
            for (int m = 0; m < 4; m++)
                afr[m] = *(const bf16x8*)(ab + m * (16 * LS));
            #pragma unroll
            for (int m = 0; m < 4; m++)
                #pragma unroll
                for (int p = 0; p < 4; p++)
                    acc[m][p] = __builtin_amdgcn_mfma_f32_16x16x32_bf16(
                        afr[m], bfr[p], acc[m][p], 0, 0, 0);
        }

        // ---- elementwise -> h(t) staged in regs (committed next loop top)
        #pragma unroll
        for (int m = 0; m < 4; m++) {
            #pragma unroll
            for (int k = 0; k < 2; k++) {
                unsigned pk = 0;
                #pragma unroll
                for (int h2 = 0; h2 < 2; h2++) {
                    int r = 2 * k + h2;
                    float c = sigmoid_fast(acc[m][1][r]) * c_st[m][r]
                            + sigmoid_fast(acc[m][0][r]) * tanh_fast(acc[m][2][r]);
                    c_st[m][r] = c;
                    float h = sigmoid_fast(acc[m][3][r]) * tanh_fast(c);
                    pk |= ((unsigned)f2bf(h)) << (16 * h2);
                }
                hn[m][k] = pk;
            }
        }
        __syncthreads();
    }

    // ---- final commit: Hb = h(15), Xb = own h_in rows (parked at t=15)
    #pragma unroll
    for (int m = 0; m < 4; m++)
        #pragma unroll
        for (int k = 0; k < 2; k++) {
            int a = (m * 16 + quad * 4 + 2 * k) * LS + wv * 16 + col;
            unsigned pk = hn[m][k];
            lds[HOFF + a]      = (ushort)pk;
            lds[HOFF + a + LS] = (ushort)(pk >> 16);
        }
    {
        u32x4* dp = (u32x4*)(lds + XOFF + grow * LS);
        dp[gpart] = P0; dp[gpart + 10] = P1;
    }
    __syncthreads();

    // ---- out = relu([h_last | h_in] @ [W_l | W_r]^T + b_l)
    // waves 0..7: (m = wv&3, phalf = wv>>2); waves 8,9 idle (no barriers after)
    if (wv < 8) {
        const int m = wv & 3, pb = (wv >> 2) * 4;
        f32x4 acc2[4];
        #pragma unroll
        for (int p = 0; p < 4; p++) {
            float b = bl[(pb + p) * 16 + col];
            acc2[p] = (f32x4){b, b, b, b};
        }
        const u32x4* wq2 = (const u32x4*)g_wlrfrag + lane;
        #pragma unroll
        for (int kc = 0; kc < 10; kc++) {
            bf16x8 bfr[4];
            #pragma unroll
            for (int p = 0; p < 4; p++) {
                u32x4 u = wq2[(kc * 8 + pb + p) * 64];
                bfr[p] = *(const bf16x8*)&u;
            }
            const ushort* ab = ((kc < 5) ? (lds + HOFF + kc * 32)
                                         : (lds + XOFF + (kc - 5) * 32))
                               + (m * 16 + col) * LS + quad * 8;
            bf16x8 afr = *(const bf16x8*)ab;
            #pragma unroll
            for (int p = 0; p < 4; p++)
                acc2[p] = __builtin_amdgcn_mfma_f32_16x16x32_bf16(afr, bfr[p], acc2[p], 0, 0, 0);
        }
        #pragma unroll
        for (int p = 0; p < 4; p++) {
            int ocol = (pb + p) * 16 + col;
            #pragma unroll
            for (int r = 0; r < 4; r++) {
                int node = nb + m * 16 + quad * 4 + r;
                if (node < N_NODES) {
                    float v = acc2[p][r];
                    out[node * OUT_CH + ocol] = v > 0.f ? v : 0.f;
                }
            }
        }
    }
}

// ---------------------------------------------------------------------------
// FALLBACK: static 43KB LDS, 2 barriers/step, all weights streamed — used
// only if the dynamic-LDS attribute probe fails.
// ---------------------------------------------------------------------------
__launch_bounds__(640)
__global__ void lstm_sage_sb(const int* __restrict__ edge_src,
                             const float* __restrict__ bl,
                             float* __restrict__ out)
{
    __shared__ ushort Xb[64 * LS];
    __shared__ ushort Hb[64 * LS];

    const int tid  = threadIdx.x;
    const int lane = tid & 63;
    const int wv   = tid >> 6;
    const int col  = lane & 15, quad = lane >> 4;
    const int nb   = blockIdx.x * 64;

    float bG4[4];
    #pragma unroll
    for (int p = 0; p < 4; p++) bG4[p] = g_bsum[p * 160 + wv * 16 + col];

    for (int i = tid; i < 64 * LS; i += 640) Hb[i] = 0;

    float c_st[4][4];
    #pragma unroll
    for (int m = 0; m < 4; m++)
        #pragma unroll
        for (int r = 0; r < 4; r++) c_st[m][r] = 0.f;

    unsigned hn[4][2];

    const int grow  = tid / 10;
    const int gpart = tid - grow * 10;
    const int node_g = nb + grow;
    const int sbase = (node_g < N_NODES ? node_g : 0) * DEG;

    u32x4 P0, P1;
    {
        int s = edge_src[sbase];
        const u32x4* sp = (const u32x4*)(g_hin + s * F_DIM);
        P0 = sp[gpart]; P1 = sp[gpart + 10];
    }
    int snext = edge_src[sbase + 1];

    #pragma unroll 1
    for (int t = 0; t < NSTEP; t++) {
        if (t > 0) {
            #pragma unroll
            for (int m = 0; m < 4; m++)
                #pragma unroll
                for (int k = 0; k < 2; k++) {
                    int a = (m * 16 + quad * 4 + 2 * k) * LS + wv * 16 + col;
                    unsigned pk = hn[m][k];
                    Hb[a]      = (ushort)pk;
                    Hb[a + LS] = (ushort)(pk >> 16);
                }
        }
        {
            u32x4* dp = (u32x4*)(Xb + grow * LS);
            dp[gpart] = P0; dp[gpart + 10] = P1;
        }
        __syncthreads();

        {
            const u32x4* sp = (t < NSTEP - 1)
                ? (const u32x4*)(g_hin + snext * F_DIM)
                : (const u32x4*)(g_hin + (node_g < N_NODES ? node_g : 0) * F_DIM);
            P0 = sp[gpart]; P1 = sp[gpart + 10];
            snext = edge_src[sbase + ((t + 2 < DEG) ? t + 2 : 0)];
        }

        f32x4 acc[4][4];
        #pragma unroll
        for (int m = 0; m < 4; m++)
            #pragma unroll
            for (int p = 0; p < 4; p++)
                acc[m][p] = (f32x4){bG4[p], bG4[p], bG4[p], bG4[p]};

        const u32x4* wq = (const u32x4*)g_wfrag + wv * 40 * 64 + lane;
        #pragma unroll
        for (int kc = 0; kc < 10; kc++) {
            bf16x8 bfr[4];
            #pragma unroll
            for (int p = 0; p < 4; p++) {
                u32x4 u = wq[(kc * 4 + p) * 64];
                bfr[p] = *(const bf16x8*)&u;
            }
            const ushort* ab = ((kc < 5) ? (Xb + kc * 32) : (Hb + (kc - 5) * 32))
                               + col * LS + quad * 8;
            bf16x8 afr[4];
            #pragma unroll
            for (int m = 0; m < 4; m++)
                afr[m] = *(const bf16x8*)(ab + m * (16 * LS));
            #pragma unroll
            for (int m = 0; m < 4; m++)
                #pragma unroll
                for (int p = 0; p < 4; p++)
                    acc[m][p] = __builtin_amdgcn_mfma_f32_16x16x32_bf16(
                        afr[m], bfr[p], acc[m][p], 0, 0, 0);
        }
        #pragma unroll
        for (int m = 0; m < 4; m++) {
            #pragma unroll
            for (int k = 0; k < 2; k++) {
                unsigned pk = 0;
                #pragma unroll
                for (int h2 = 0; h2 < 2; h2++) {
                    int r = 2 * k + h2;
                    float c = sigmoid_fast(acc[m][1][r]) * c_st[m][r]
                            + sigmoid_fast(acc[m][0][r]) * tanh_fast(acc[m][2][r]);
                    c_st[m][r] = c;
                    float h = sigmoid_fast(acc[m][3][r]) * tanh_fast(c);
                    pk |= ((unsigned)f2bf(h)) << (16 * h2);
                }
                hn[m][k] = pk;
            }
        }
        __syncthreads();
    }

    #pragma unroll
    for (int m = 0; m < 4; m++)
        #pragma unroll
        for (int k = 0; k < 2; k++) {
            int a = (m * 16 + quad * 4 + 2 * k) * LS + wv * 16 + col;
            unsigned pk = hn[m][k];
            Hb[a]      = (ushort)pk;
            Hb[a + LS] = (ushort)(pk >> 16);
        }
    {
        u32x4* dp = (u32x4*)(Xb + grow * LS);
        dp[gpart] = P0; dp[gpart + 10] = P1;
    }
    __syncthreads();

    if (wv < 8) {
        const int m = wv & 3, pb = (wv >> 2) * 4;
        f32x4 acc[4];
        #pragma unroll
        for (int p = 0; p < 4; p++) {
            float b = bl[(pb + p) * 16 + col];
            acc[p] = (f32x4){b, b, b, b};
        }
        const u32x4* wq2 = (const u32x4*)g_wlrfrag + lane;
        #pragma unroll
        for (int kc = 0; kc < 10; kc++) {
            bf16x8 bfr[4];
            #pragma unroll
            for (int p = 0; p < 4; p++) {
                u32x4 u = wq2[(kc * 8 + pb + p) * 64];
                bfr[p] = *(const bf16x8*)&u;
            }
            const ushort* ab = ((kc < 5) ? (Hb + kc * 32) : (Xb + (kc - 5) * 32))
                               + (m * 16 + col) * LS + quad * 8;
            bf16x8 afr = *(const bf16x8*)ab;
            #pragma unroll
            for (int p = 0; p < 4; p++)
                acc[p] = __builtin_amdgcn_mfma_f32_16x16x32_bf16(afr, bfr[p], acc[p], 0, 0, 0);
        }
        #pragma unroll
        for (int p = 0; p < 4; p++) {
            int ocol = (pb + p) * 16 + col;
            #pragma unroll
            for (int r = 0; r < 4; r++) {
                int node = nb + m * 16 + quad * 4 + r;
                if (node < N_NODES) {
                    float v = acc[p][r];
                    out[node * OUT_CH + ocol] = v > 0.f ? v : 0.f;
                }
            }
        }
    }
}

extern "C" void kernel_launch(void* const* d_in, const int* in_sizes, int n_in,
                              void* d_out, int out_size, void* d_ws, size_t ws_size,
                              hipStream_t stream)
{
    const float* x      = (const float*)d_in[0];
    const int*   tids   = (const int*)  d_in[1];
    const int*   esrc   = (const int*)  d_in[2];   // edge_index[0] = src (dst sorted, DEG each)
    const float* emb    = (const float*)d_in[3];
    const float* Wih    = (const float*)d_in[4];
    const float* Whh    = (const float*)d_in[5];
    const float* bih    = (const float*)d_in[6];
    const float* bhh    = (const float*)d_in[7];
    const float* Wl     = (const float*)d_in[8];
    const float* blin   = (const float*)d_in[9];
    const float* Wr     = (const float*)d_in[10];
    float* out = (float*)d_out;

    hipLaunchKernelGGL(pack_kernel, dim3(123), dim3(256), 0, stream,
                       Wih, Whh, bih, bhh, Wl, Wr);
    hipLaunchKernelGGL(build_hin, dim3((N_NODES * F_DIM + 255) / 256), dim3(256), 0, stream,
                       x, tids, emb);

    // 43008 (Xb+Hb single buffers) + 112640 (11 resident frags) = 155648 B
    const int dbShmem = (2 * 64 * LS + NRES * 10 * 64 * 8) * (int)sizeof(ushort);
    (void)hipFuncSetAttribute((const void*)lstm_sage_r11,
                              hipFuncAttributeMaxDynamicSharedMemorySize, dbShmem);
    hipFuncAttributes fa;
    bool dbOk = (hipFuncGetAttributes(&fa, (const void*)lstm_sage_r11) == hipSuccess) &&
                (fa.maxDynamicSharedSizeBytes >= dbShmem);

    if (dbOk) {
        hipLaunchKernelGGL(lstm_sage_r11, dim3((N_NODES + 63) / 64), dim3(640),
                           dbShmem, stream, esrc, blin, out);
    } else {
        hipLaunchKernelGGL(lstm_sage_sb, dim3((N_NODES + 63) / 64), dim3(640),
                           0, stream, esrc, blin, out);
    }
}